// Round 10
// baseline (415.590 us; speedup 1.0000x reference)
//
#include <hip/hip_runtime.h>
#include <hip/hip_fp16.h>

typedef _Float16 half8 __attribute__((ext_vector_type(8)));
typedef float f32x4 __attribute__((ext_vector_type(4)));

#define NXCD 8

// ---------------- helpers ----------------
__device__ __forceinline__ int rfl(int v) { return __builtin_amdgcn_readfirstlane(v); }

__device__ __forceinline__ int lowerb(const int* a, int n, int v) {
    int lo = 0, hi = n;
    while (lo < hi) { int m = (lo + hi) >> 1; if (a[m] < v) lo = m + 1; else hi = m; }
    return lo;
}

// ---------------- setup kernels ----------------
__global__ void k_zero_i32(int* __restrict__ p, int n) {
    int i = blockIdx.x * blockDim.x + threadIdx.x;
    if (i < n) p[i] = 0;
}

// Phase A: bucket edges by dst-range r into sub-bucket (w, r), w = blockIdx&7.
// Two-phase LDS counting + one padded-line global atomic per (block,bucket).
__global__ __launch_bounds__(256) void k_bucket(const int* __restrict__ src,
        const int* __restrict__ dst, int* __restrict__ bcnt, int2* __restrict__ bkt,
        int E, int N, int cap, int csz) {
    int w = blockIdx.x & (NXCD - 1);
    int e0 = blockIdx.x * csz;
    int e1 = min(e0 + csz, E);
    __shared__ int lcnt[NXCD];
    __shared__ int gbase[NXCD];
    if (threadIdx.x < NXCD) lcnt[threadIdx.x] = 0;
    __syncthreads();
    int dd[4], ss[4], rr[4], ll[4];
    #pragma unroll
    for (int it = 0; it < 4; ++it) {
        int e = e0 + it * 256 + threadIdx.x;
        ll[it] = -1;
        dd[it] = 0; ss[it] = 0; rr[it] = 0;
        if (e < e1) {
            int d = dst[e], s = src[e];
            int r = (int)(((long long)d << 3) / N);
            dd[it] = d; ss[it] = s; rr[it] = r;
            ll[it] = atomicAdd(&lcnt[r], 1);
        }
    }
    __syncthreads();
    if (threadIdx.x < NXCD)
        gbase[threadIdx.x] = atomicAdd(&bcnt[(w * NXCD + threadIdx.x) * 16], lcnt[threadIdx.x]);
    __syncthreads();
    #pragma unroll
    for (int it = 0; it < 4; ++it) {
        if (ll[it] >= 0) {
            bkt[(size_t)(w * NXCD + rr[it]) * cap + gbase[rr[it]] + ll[it]] =
                make_int2(dd[it], ss[it]);
        }
    }
}

// Phase B1: per-(dst, src-slice) histogram. XCD x consumes buckets (*, x);
// segcnt atomics land in x's local slice. avg 2 edges per (d,c) counter.
__global__ __launch_bounds__(256) void k_hist2(const int2* __restrict__ bkt,
        const int* __restrict__ bcnt, int* __restrict__ segcnt, int cap, int N) {
    int x = blockIdx.x & (NXCD - 1);
    int lb = blockIdx.x >> 3, nlb = gridDim.x >> 3;
    for (int w = 0; w < NXCD; ++w) {
        int cnt = rfl(bcnt[(w * NXCD + x) * 16]);
        const int2* b = bkt + (size_t)(w * NXCD + x) * cap;
        for (int i = lb * 256 + threadIdx.x; i < cnt; i += nlb * 256) {
            int2 p = b[i];
            int c = (int)(((long long)p.y << 3) / N);
            atomicAdd(&segcnt[(size_t)p.x * 8 + c], 1);
        }
    }
}

// scan phase 1: deg = sum of node's 8 segcnt; dinv; block-local scan of deg
__global__ __launch_bounds__(256) void k_scan1(const int* __restrict__ segcnt,
        int* __restrict__ locscan, int* __restrict__ bsum, float* __restrict__ dinv, int N) {
    __shared__ int sh[256];
    int t = threadIdx.x;
    int i = blockIdx.x * 256 + t;
    int d = 0;
    if (i < N) {
        const int4* p = (const int4*)(segcnt + (size_t)i * 8);
        int4 a = p[0], b = p[1];
        d = a.x + a.y + a.z + a.w + b.x + b.y + b.z + b.w;
        dinv[i] = rsqrtf((float)d + 1.0f);
    }
    sh[t] = d;
    __syncthreads();
    int v = d;
    #pragma unroll
    for (int o = 1; o < 256; o <<= 1) {
        int u = (t >= o) ? sh[t - o] : 0;
        __syncthreads();
        v += u;
        sh[t] = v;
        __syncthreads();
    }
    if (i < N) locscan[i] = v - d;
    if (t == 255) bsum[blockIdx.x] = v;
}

__global__ __launch_bounds__(256) void k_scan2(const int* __restrict__ bsum,
        int* __restrict__ boff, int* __restrict__ off, int nb, int N) {
    __shared__ int sh[256];
    int t = threadIdx.x;
    int d = (t < nb) ? bsum[t] : 0;
    sh[t] = d;
    __syncthreads();
    int v = d;
    #pragma unroll
    for (int o = 1; o < 256; o <<= 1) {
        int u = (t >= o) ? sh[t - o] : 0;
        __syncthreads();
        v += u;
        sh[t] = v;
        __syncthreads();
    }
    if (t < nb) boff[t] = v - d;
    if (t == 255) off[N] = v;
}

// scan phase 3: off[d] = global base; segcur[d*8+c] = segment-c start offset
__global__ __launch_bounds__(256) void k_scan3(const int* __restrict__ locscan,
        const int* __restrict__ boff, const int* __restrict__ segcnt,
        int* __restrict__ off, int* __restrict__ segcur, int N) {
    int i = blockIdx.x * 256 + threadIdx.x;
    if (i < N) {
        int run = locscan[i] + boff[blockIdx.x];
        off[i] = run;
        #pragma unroll
        for (int c = 0; c < 8; ++c) {
            segcur[(size_t)i * 8 + c] = run;
            run += segcnt[(size_t)i * 8 + c];
        }
    }
}

// Phase B2: CSR scatter into c-sorted per-dst segments (post-run, segcur[d*8+c]
// equals the END of segment c). XCD-local atomics and writes.
__global__ __launch_bounds__(256) void k_scatter_b(const int2* __restrict__ bkt,
        const int* __restrict__ bcnt, int* __restrict__ segcur, int* __restrict__ ssrc,
        int cap, int N) {
    int x = blockIdx.x & (NXCD - 1);
    int lb = blockIdx.x >> 3, nlb = gridDim.x >> 3;
    for (int w = 0; w < NXCD; ++w) {
        int cnt = rfl(bcnt[(w * NXCD + x) * 16]);
        const int2* b = bkt + (size_t)(w * NXCD + x) * cap;
        for (int i = lb * 256 + threadIdx.x; i < cnt; i += nlb * 256) {
            int2 p = b[i];
            int c = (int)(((long long)p.y << 3) / N);
            int pos = atomicAdd(&segcur[(size_t)p.x * 8 + c], 1);
            ssrc[pos] = p.y;
        }
    }
}

// pack W1 and W2 (128x128 f32 row-major) into fp16 MFMA B-fragment order
__global__ __launch_bounds__(256) void k_prep_w2(const float* __restrict__ W1,
        const float* __restrict__ W2, _Float16* __restrict__ wfrag) {
    int idx = blockIdx.x * 256 + threadIdx.x;
    if (idx >= 32768) return;
    const float* W = (idx < 16384) ? W1 : W2;
    int id = idx & 16383;
    int j  = id & 7;
    int l  = (id >> 3) & 63;
    int t  = (id >> 9) & 3;
    int nt = id >> 11;
    int k  = t * 32 + (l >> 4) * 8 + j;
    int n  = nt * 16 + (l & 15);
    wfrag[idx] = (_Float16)W[k * 128 + n];
}

// MFMA GEMM: Hh[r][c] = sum_k X[r][k] * W[k][c]  (A from f32 or fp16, f32 acc, fp16 out)
template <bool AF32>
__global__ __launch_bounds__(256, 2) void k_gemm_mfma(const void* __restrict__ Xv,
        const _Float16* __restrict__ wfrag, _Float16* __restrict__ Hh, int nrows) {
    int w = threadIdx.x >> 6, l = threadIdx.x & 63;
    int gw = blockIdx.x * 4 + w;
    int ch = gw & 1;
    int strip0 = gw >> 1;
    int sstride = gridDim.x * 2;

    half8 b[4][4];
    #pragma unroll
    for (int q = 0; q < 4; ++q)
        #pragma unroll
        for (int t = 0; t < 4; ++t)
            b[q][t] = *(const half8*)&wfrag[(((ch * 4 + q) * 4 + t) * 64 + l) * 8];

    int row_in = l & 15;
    int kb = l >> 4;
    int nstrips = (nrows + 15) >> 4;
    for (int s = strip0; s < nstrips; s += sstride) {
        int m0 = s << 4;
        int rl = m0 + row_in; if (rl > nrows - 1) rl = nrows - 1;
        half8 a[4];
        if constexpr (AF32) {
            const float* xr = (const float*)Xv + (size_t)rl * 128 + kb * 8;
            #pragma unroll
            for (int t = 0; t < 4; ++t) {
                float4 u0 = *(const float4*)(xr + t * 32);
                float4 u1 = *(const float4*)(xr + t * 32 + 4);
                half8 av = { (_Float16)u0.x, (_Float16)u0.y, (_Float16)u0.z, (_Float16)u0.w,
                             (_Float16)u1.x, (_Float16)u1.y, (_Float16)u1.z, (_Float16)u1.w };
                a[t] = av;
            }
        } else {
            const _Float16* xr = (const _Float16*)Xv + (size_t)rl * 128 + kb * 8;
            #pragma unroll
            for (int t = 0; t < 4; ++t) a[t] = *(const half8*)(xr + t * 32);
        }

        f32x4 acc[4];
        #pragma unroll
        for (int q = 0; q < 4; ++q) acc[q] = (f32x4){0.f, 0.f, 0.f, 0.f};
        #pragma unroll
        for (int t = 0; t < 4; ++t)
            #pragma unroll
            for (int q = 0; q < 4; ++q)
                acc[q] = __builtin_amdgcn_mfma_f32_16x16x32_f16(a[t], b[q][t], acc[q], 0, 0, 0);

        int orow = m0 + (l >> 4) * 4;
        int ocol = ch * 64 + (l & 15);
        _Float16* op = Hh + (size_t)orow * 128 + ocol;
        #pragma unroll
        for (int r = 0; r < 4; ++r) {
            if (orow + r < nrows) {
                #pragma unroll
                for (int q = 0; q < 4; ++q)
                    op[(size_t)r * 128 + q * 16] = (_Float16)acc[q][r];
            }
        }
    }
}

// GCN aggregate v2: one wave owns 8 consecutive dsts (16 f32 acc VGPRs,
// statically indexed), sweeps src-slices c=0..7 via c-sorted segments.
// All waves sweep c together -> instantaneous gather working set ~1 slice
// (1.6 MB fp16) which is L2-resident, instead of all 12.8 MB of H.
__global__ __launch_bounds__(256) void k_agg(const __half* __restrict__ Hh,
        const float* __restrict__ dinv, const int* __restrict__ off,
        const int* __restrict__ segcur, const int* __restrict__ ssrc,
        const float* __restrict__ bias, __half* __restrict__ Oh, int N) {
    int lane = threadIdx.x & 63;
    int xcd = blockIdx.x & (NXCD - 1);
    int lw  = (blockIdx.x >> 3) * 4 + (threadIdx.x >> 6);
    int nlw = (gridDim.x >> 3) * 4;
    int lo = (int)(((long long)xcd * N) >> 3);
    int hi = (int)(((long long)(xcd + 1) * N) >> 3);
    float2 bv = *(const float2*)&bias[2 * lane];
    for (int base = lo + lw * 8; base < hi; base += nlw * 8) {
        float2 acc[8];
        float dv[8];
        #pragma unroll
        for (int k = 0; k < 8; ++k) {
            int d = base + k;
            if (d < hi) {
                float dd = dinv[d];
                dv[k] = dd;
                float2 hv = __half22float2(((const __half2*)(Hh + (size_t)d * 128))[lane]);
                acc[k].x = hv.x * dd * dd;
                acc[k].y = hv.y * dd * dd;
            } else {
                dv[k] = 0.f; acc[k].x = 0.f; acc[k].y = 0.f;
            }
        }
        for (int c = 0; c < 8; ++c) {        // sequential src-slice sweep
            #pragma unroll
            for (int k = 0; k < 8; ++k) {
                int d = base + k;
                if (d >= hi) continue;
                int j0 = rfl((c == 0) ? off[d] : segcur[(size_t)d * 8 + c - 1]);
                int j1 = rfl(segcur[(size_t)d * 8 + c]);
                float dd = dv[k];
                for (int j = j0; j < j1; ++j) {
                    int s = rfl(ssrc[j]);
                    float m = dinv[s] * dd;
                    float2 h = __half22float2(((const __half2*)(Hh + (size_t)s * 128))[lane]);
                    acc[k].x = fmaf(h.x, m, acc[k].x);
                    acc[k].y = fmaf(h.y, m, acc[k].y);
                }
            }
        }
        #pragma unroll
        for (int k = 0; k < 8; ++k) {
            int d = base + k;
            if (d < hi) {
                float a0 = fmaxf(acc[k].x + bv.x, 0.f);
                float a1 = fmaxf(acc[k].y + bv.y, 0.f);
                ((__half2*)(Oh + (size_t)d * 128))[lane] = __floats2half2_rn(a0, a1);
            }
        }
    }
}

// parallel partial mean-pool over fp16 features
__global__ __launch_bounds__(256) void k_pool_h(const __half* __restrict__ X,
        const int* __restrict__ batch, float* __restrict__ pooled, int N) {
    int c = threadIdx.x & 127, sub = threadIdx.x >> 7;
    int chunk = (N + gridDim.x - 1) / gridDim.x;
    int b = blockIdx.x * chunk, e = min(b + chunk, N);
    float acc = 0.f;
    int cg = -1;
    for (int n = b + sub; n < e; n += 2) {
        int g = batch[n];
        if (g != cg) {
            if (cg >= 0) atomicAdd(&pooled[cg * 128 + c], acc);
            acc = 0.f;
            cg = g;
        }
        acc += __half2float(X[(size_t)n * 128 + c]);
    }
    if (cg >= 0) atomicAdd(&pooled[cg * 128 + c], acc);
}

__global__ void k_final(const float* __restrict__ P, const int* __restrict__ batch,
        const float* __restrict__ Wl, const float* __restrict__ bl,
        float* __restrict__ out, int G, int CO, int N) {
    int t = blockIdx.x * blockDim.x + threadIdx.x;
    if (t >= G * CO) return;
    int g = t / CO, o = t % CO;
    int cnt = lowerb(batch, N, g + 1) - lowerb(batch, N, g);
    float inv = cnt > 0 ? 1.0f / (float)cnt : 0.0f;
    float acc = bl[o];
    for (int k = 0; k < 128; ++k) acc += P[g * 128 + k] * inv * Wl[k * CO + o];
    out[t] = acc;
}

// ---------------- launcher ----------------
extern "C" void kernel_launch(void* const* d_in, const int* in_sizes, int n_in,
                              void* d_out, int out_size, void* d_ws, size_t ws_size,
                              hipStream_t stream) {
    const float* x     = (const float*)d_in[0];
    const int*   ei    = (const int*)d_in[1];
    const int*   batch = (const int*)d_in[2];
    const float* W1e   = (const float*)d_in[5];
    const float* b1e   = (const float*)d_in[6];
    const float* W2e   = (const float*)d_in[9];
    const float* b2e   = (const float*)d_in[10];
    const float* Wlin  = (const float*)d_in[11];
    const float* blin  = (const float*)d_in[12];
    float* out = (float*)d_out;

    int N  = in_sizes[0] / 128;
    int E  = in_sizes[1] / 2;
    int CO = in_sizes[12];          // 10
    int G  = out_size / CO;         // 64

    const int* src = ei;
    const int* dst = ei + E;

    int cap = E / 64 + 8192;        // sub-bucket capacity (uniform-random slack)

    // workspace layout: zeroed region [segcnt | bcnt | pooled] is contiguous
    _Float16* hh  = (_Float16*)d_ws;                 // N*128 fp16
    _Float16* x1h = hh + (size_t)N * 128;            // N*128 fp16
    int2* bkt     = (int2*)(x1h + (size_t)N * 128);  // 64*cap int2
    int* segcnt   = (int*)(bkt + (size_t)64 * cap);  // N*8
    int* bcnt     = segcnt + (size_t)N * 8;          // 1024
    float* pooled = (float*)(bcnt + 1024);           // G*128
    int* off      = (int*)(pooled + (size_t)G * 128);// N+1 (pad 4)
    int* segcur   = off + (N + 4);                   // N*8
    int* ssrc     = segcur + (size_t)N * 8;          // E
    int* locscan  = ssrc + E;                        // N
    int* bsum     = locscan + N;                     // 256
    int* boff     = bsum + 256;                      // 256
    float* dinv   = (float*)(boff + 256);            // N
    _Float16* wfrag = (_Float16*)(dinv + N);         // 32768 halves (W1|W2)

    int nb = (N + 255) / 256;
    int nbkt_blocks = 1024;                          // csz <= 1024 = 4 iters x 256
    int csz = (E + nbkt_blocks - 1) / nbkt_blocks;
    int nzero = N * 8 + 1024 + G * 128;              // segcnt + bcnt + pooled

    k_zero_i32<<<(nzero + 255) / 256, 256, 0, stream>>>(segcnt, nzero);
    k_prep_w2<<<128, 256, 0, stream>>>(W1e, W2e, wfrag);

    k_bucket<<<nbkt_blocks, 256, 0, stream>>>(src, dst, bcnt, bkt, E, N, cap, csz);
    k_hist2<<<512, 256, 0, stream>>>(bkt, bcnt, segcnt, cap, N);
    k_scan1<<<nb, 256, 0, stream>>>(segcnt, locscan, bsum, dinv, N);
    k_scan2<<<1, 256, 0, stream>>>(bsum, boff, off, nb, N);
    k_scan3<<<nb, 256, 0, stream>>>(locscan, boff, segcnt, off, segcur, N);
    k_scatter_b<<<512, 256, 0, stream>>>(bkt, bcnt, segcur, ssrc, cap, N);

    int nstrips = (N + 15) / 16;
    int gemm_blocks = (nstrips * 2 + 3) / 4;
    int agg_blocks = ((N / 8 + 63) / 64 + 1) * 8;    // ~1 wave per 8-dst group, x8 XCD

    // layer 1 (A direct from f32 x)
    k_gemm_mfma<true><<<gemm_blocks, 256, 0, stream>>>((const void*)x, wfrag, hh, N);
    k_agg<<<agg_blocks, 256, 0, stream>>>((const __half*)hh, dinv, off, segcur, ssrc,
                                          b1e, (__half*)x1h, N);
    // layer 2
    k_gemm_mfma<false><<<gemm_blocks, 256, 0, stream>>>((const void*)x1h, wfrag + 16384, hh, N);
    k_agg<<<agg_blocks, 256, 0, stream>>>((const __half*)hh, dinv, off, segcur, ssrc,
                                          b2e, (__half*)x1h, N);

    k_pool_h<<<512, 256, 0, stream>>>((const __half*)x1h, batch, pooled, N);
    k_final<<<3, 256, 0, stream>>>(pooled, batch, Wlin, blin, out, G, CO, N);
}

// Round 11
// 220.368 us; speedup vs baseline: 1.8859x; 1.8859x over previous
//
#include <hip/hip_runtime.h>
#include <hip/hip_fp16.h>

typedef _Float16 half8 __attribute__((ext_vector_type(8)));
typedef float f32x4 __attribute__((ext_vector_type(4)));

#define NXCD 8

// ---------------- helpers ----------------
__device__ __forceinline__ int rfl(int v) { return __builtin_amdgcn_readfirstlane(v); }

__device__ __forceinline__ int lowerb(const int* a, int n, int v) {
    int lo = 0, hi = n;
    while (lo < hi) { int m = (lo + hi) >> 1; if (a[m] < v) lo = m + 1; else hi = m; }
    return lo;
}

// ---------------- setup kernels ----------------
__global__ void k_zero_i32(int* __restrict__ p, int n) {
    int i = blockIdx.x * blockDim.x + threadIdx.x;
    if (i < n) p[i] = 0;
}

// Phase A: bucket edges by dst-range r into sub-bucket (w, r), w = blockIdx&7.
// Two-phase LDS counting + one padded-line global atomic per (block,bucket).
__global__ __launch_bounds__(256) void k_bucket(const int* __restrict__ src,
        const int* __restrict__ dst, int* __restrict__ bcnt, int2* __restrict__ bkt,
        int E, int N, int cap, int csz) {
    int w = blockIdx.x & (NXCD - 1);
    int e0 = blockIdx.x * csz;
    int e1 = min(e0 + csz, E);
    __shared__ int lcnt[NXCD];
    __shared__ int gbase[NXCD];
    if (threadIdx.x < NXCD) lcnt[threadIdx.x] = 0;
    __syncthreads();
    int dd[4], ss[4], rr[4], ll[4];
    #pragma unroll
    for (int it = 0; it < 4; ++it) {
        int e = e0 + it * 256 + threadIdx.x;
        ll[it] = -1;
        dd[it] = 0; ss[it] = 0; rr[it] = 0;
        if (e < e1) {
            int d = dst[e], s = src[e];
            int r = (int)(((long long)d << 3) / N);
            dd[it] = d; ss[it] = s; rr[it] = r;
            ll[it] = atomicAdd(&lcnt[r], 1);
        }
    }
    __syncthreads();
    if (threadIdx.x < NXCD)
        gbase[threadIdx.x] = atomicAdd(&bcnt[(w * NXCD + threadIdx.x) * 16], lcnt[threadIdx.x]);
    __syncthreads();
    #pragma unroll
    for (int it = 0; it < 4; ++it) {
        if (ll[it] >= 0) {
            bkt[(size_t)(w * NXCD + rr[it]) * cap + gbase[rr[it]] + ll[it]] =
                make_int2(dd[it], ss[it]);
        }
    }
}

// Phase B1: per-(dst, src-slice) histogram. XCD x consumes buckets (*, x).
__global__ __launch_bounds__(256) void k_hist2(const int2* __restrict__ bkt,
        const int* __restrict__ bcnt, int* __restrict__ segcnt, int cap, int N) {
    int x = blockIdx.x & (NXCD - 1);
    int lb = blockIdx.x >> 3, nlb = gridDim.x >> 3;
    for (int w = 0; w < NXCD; ++w) {
        int cnt = rfl(bcnt[(w * NXCD + x) * 16]);
        const int2* b = bkt + (size_t)(w * NXCD + x) * cap;
        for (int i = lb * 256 + threadIdx.x; i < cnt; i += nlb * 256) {
            int2 p = b[i];
            int c = (int)(((long long)p.y << 3) / N);
            atomicAdd(&segcnt[(size_t)p.x * 8 + c], 1);
        }
    }
}

// scan phase 1: deg = sum of node's 8 segcnt; dinv; block-local scan of deg
__global__ __launch_bounds__(256) void k_scan1(const int* __restrict__ segcnt,
        int* __restrict__ locscan, int* __restrict__ bsum, float* __restrict__ dinv, int N) {
    __shared__ int sh[256];
    int t = threadIdx.x;
    int i = blockIdx.x * 256 + t;
    int d = 0;
    if (i < N) {
        const int4* p = (const int4*)(segcnt + (size_t)i * 8);
        int4 a = p[0], b = p[1];
        d = a.x + a.y + a.z + a.w + b.x + b.y + b.z + b.w;
        dinv[i] = rsqrtf((float)d + 1.0f);
    }
    sh[t] = d;
    __syncthreads();
    int v = d;
    #pragma unroll
    for (int o = 1; o < 256; o <<= 1) {
        int u = (t >= o) ? sh[t - o] : 0;
        __syncthreads();
        v += u;
        sh[t] = v;
        __syncthreads();
    }
    if (i < N) locscan[i] = v - d;
    if (t == 255) bsum[blockIdx.x] = v;
}

__global__ __launch_bounds__(256) void k_scan2(const int* __restrict__ bsum,
        int* __restrict__ boff, int* __restrict__ off, int nb, int N) {
    __shared__ int sh[256];
    int t = threadIdx.x;
    int d = (t < nb) ? bsum[t] : 0;
    sh[t] = d;
    __syncthreads();
    int v = d;
    #pragma unroll
    for (int o = 1; o < 256; o <<= 1) {
        int u = (t >= o) ? sh[t - o] : 0;
        __syncthreads();
        v += u;
        sh[t] = v;
        __syncthreads();
    }
    if (t < nb) boff[t] = v - d;
    if (t == 255) off[N] = v;
}

// scan phase 3: off[d] = global base; segcur[d*8+c] = segment-c start offset
__global__ __launch_bounds__(256) void k_scan3(const int* __restrict__ locscan,
        const int* __restrict__ boff, const int* __restrict__ segcnt,
        int* __restrict__ off, int* __restrict__ segcur, int N) {
    int i = blockIdx.x * 256 + threadIdx.x;
    if (i < N) {
        int run = locscan[i] + boff[blockIdx.x];
        off[i] = run;
        #pragma unroll
        for (int c = 0; c < 8; ++c) {
            segcur[(size_t)i * 8 + c] = run;
            run += segcnt[(size_t)i * 8 + c];
        }
    }
}

// Phase B2: CSR scatter into c-sorted per-dst segments. XCD-local atomics/writes.
// Result: each dst's edge list (off[d]..off[d+1]) is contiguous, sorted by
// src-slice -> soft cross-wave slice sync in k_agg without serialization.
__global__ __launch_bounds__(256) void k_scatter_b(const int2* __restrict__ bkt,
        const int* __restrict__ bcnt, int* __restrict__ segcur, int* __restrict__ ssrc,
        int cap, int N) {
    int x = blockIdx.x & (NXCD - 1);
    int lb = blockIdx.x >> 3, nlb = gridDim.x >> 3;
    for (int w = 0; w < NXCD; ++w) {
        int cnt = rfl(bcnt[(w * NXCD + x) * 16]);
        const int2* b = bkt + (size_t)(w * NXCD + x) * cap;
        for (int i = lb * 256 + threadIdx.x; i < cnt; i += nlb * 256) {
            int2 p = b[i];
            int c = (int)(((long long)p.y << 3) / N);
            int pos = atomicAdd(&segcur[(size_t)p.x * 8 + c], 1);
            ssrc[pos] = p.y;
        }
    }
}

// pack W1 and W2 (128x128 f32 row-major) into fp16 MFMA B-fragment order
__global__ __launch_bounds__(256) void k_prep_w2(const float* __restrict__ W1,
        const float* __restrict__ W2, _Float16* __restrict__ wfrag) {
    int idx = blockIdx.x * 256 + threadIdx.x;
    if (idx >= 32768) return;
    const float* W = (idx < 16384) ? W1 : W2;
    int id = idx & 16383;
    int j  = id & 7;
    int l  = (id >> 3) & 63;
    int t  = (id >> 9) & 3;
    int nt = id >> 11;
    int k  = t * 32 + (l >> 4) * 8 + j;
    int n  = nt * 16 + (l & 15);
    wfrag[idx] = (_Float16)W[k * 128 + n];
}

// MFMA GEMM: Hh[r][c] = sum_k X[r][k] * W[k][c]  (A from f32 or fp16, f32 acc, fp16 out)
template <bool AF32>
__global__ __launch_bounds__(256, 2) void k_gemm_mfma(const void* __restrict__ Xv,
        const _Float16* __restrict__ wfrag, _Float16* __restrict__ Hh, int nrows) {
    int w = threadIdx.x >> 6, l = threadIdx.x & 63;
    int gw = blockIdx.x * 4 + w;
    int ch = gw & 1;
    int strip0 = gw >> 1;
    int sstride = gridDim.x * 2;

    half8 b[4][4];
    #pragma unroll
    for (int q = 0; q < 4; ++q)
        #pragma unroll
        for (int t = 0; t < 4; ++t)
            b[q][t] = *(const half8*)&wfrag[(((ch * 4 + q) * 4 + t) * 64 + l) * 8];

    int row_in = l & 15;
    int kb = l >> 4;
    int nstrips = (nrows + 15) >> 4;
    for (int s = strip0; s < nstrips; s += sstride) {
        int m0 = s << 4;
        int rl = m0 + row_in; if (rl > nrows - 1) rl = nrows - 1;
        half8 a[4];
        if constexpr (AF32) {
            const float* xr = (const float*)Xv + (size_t)rl * 128 + kb * 8;
            #pragma unroll
            for (int t = 0; t < 4; ++t) {
                float4 u0 = *(const float4*)(xr + t * 32);
                float4 u1 = *(const float4*)(xr + t * 32 + 4);
                half8 av = { (_Float16)u0.x, (_Float16)u0.y, (_Float16)u0.z, (_Float16)u0.w,
                             (_Float16)u1.x, (_Float16)u1.y, (_Float16)u1.z, (_Float16)u1.w };
                a[t] = av;
            }
        } else {
            const _Float16* xr = (const _Float16*)Xv + (size_t)rl * 128 + kb * 8;
            #pragma unroll
            for (int t = 0; t < 4; ++t) a[t] = *(const half8*)(xr + t * 32);
        }

        f32x4 acc[4];
        #pragma unroll
        for (int q = 0; q < 4; ++q) acc[q] = (f32x4){0.f, 0.f, 0.f, 0.f};
        #pragma unroll
        for (int t = 0; t < 4; ++t)
            #pragma unroll
            for (int q = 0; q < 4; ++q)
                acc[q] = __builtin_amdgcn_mfma_f32_16x16x32_f16(a[t], b[q][t], acc[q], 0, 0, 0);

        int orow = m0 + (l >> 4) * 4;
        int ocol = ch * 64 + (l & 15);
        _Float16* op = Hh + (size_t)orow * 128 + ocol;
        #pragma unroll
        for (int r = 0; r < 4; ++r) {
            if (orow + r < nrows) {
                #pragma unroll
                for (int q = 0; q < 4; ++q)
                    op[(size_t)r * 128 + q * 16] = (_Float16)acc[q][r];
            }
        }
    }
}

// GCN aggregate (round-9 structure: one wave per dst, 8-deep gather pipeline,
// XCD-partitioned dst ranges) over the c-sorted CSR (soft slice locality).
__global__ __launch_bounds__(256) void k_agg(const __half* __restrict__ Hh,
        const float* __restrict__ dinv, const int* __restrict__ off,
        const int* __restrict__ ssrc, const float* __restrict__ bias,
        __half* __restrict__ Oh, int N) {
    int lane = threadIdx.x & 63;
    int xcd = blockIdx.x & (NXCD - 1);
    int lw  = (blockIdx.x >> 3) * 4 + (threadIdx.x >> 6);
    int nlw = (gridDim.x >> 3) * 4;
    int lo = (int)(((long long)xcd * N) >> 3);
    int hi = (int)(((long long)(xcd + 1) * N) >> 3);
    float2 bv = *(const float2*)&bias[2 * lane];
    for (int i = lo + lw; i < hi; i += nlw) {
        int iu = rfl(i);
        float di = dinv[iu];
        int j0 = rfl(off[iu]);
        int j1 = rfl(off[iu + 1]);
        float2 hv = __half22float2(((const __half2*)(Hh + (size_t)iu * 128))[lane]);
        float sl = di * di;
        float a0 = hv.x * sl, a1 = hv.y * sl;
        int j = j0;
        for (; j + 8 <= j1; j += 8) {
            int s0 = rfl(ssrc[j]),     s1 = rfl(ssrc[j + 1]);
            int s2 = rfl(ssrc[j + 2]), s3 = rfl(ssrc[j + 3]);
            int s4 = rfl(ssrc[j + 4]), s5 = rfl(ssrc[j + 5]);
            int s6 = rfl(ssrc[j + 6]), s7 = rfl(ssrc[j + 7]);
            __half2 g0 = ((const __half2*)(Hh + (size_t)s0 * 128))[lane];
            __half2 g1 = ((const __half2*)(Hh + (size_t)s1 * 128))[lane];
            __half2 g2 = ((const __half2*)(Hh + (size_t)s2 * 128))[lane];
            __half2 g3 = ((const __half2*)(Hh + (size_t)s3 * 128))[lane];
            __half2 g4 = ((const __half2*)(Hh + (size_t)s4 * 128))[lane];
            __half2 g5 = ((const __half2*)(Hh + (size_t)s5 * 128))[lane];
            __half2 g6 = ((const __half2*)(Hh + (size_t)s6 * 128))[lane];
            __half2 g7 = ((const __half2*)(Hh + (size_t)s7 * 128))[lane];
            float m0 = dinv[s0] * di, m1 = dinv[s1] * di;
            float m2 = dinv[s2] * di, m3 = dinv[s3] * di;
            float m4 = dinv[s4] * di, m5 = dinv[s5] * di;
            float m6 = dinv[s6] * di, m7 = dinv[s7] * di;
            float2 h;
            h = __half22float2(g0); a0 = fmaf(h.x, m0, a0); a1 = fmaf(h.y, m0, a1);
            h = __half22float2(g1); a0 = fmaf(h.x, m1, a0); a1 = fmaf(h.y, m1, a1);
            h = __half22float2(g2); a0 = fmaf(h.x, m2, a0); a1 = fmaf(h.y, m2, a1);
            h = __half22float2(g3); a0 = fmaf(h.x, m3, a0); a1 = fmaf(h.y, m3, a1);
            h = __half22float2(g4); a0 = fmaf(h.x, m4, a0); a1 = fmaf(h.y, m4, a1);
            h = __half22float2(g5); a0 = fmaf(h.x, m5, a0); a1 = fmaf(h.y, m5, a1);
            h = __half22float2(g6); a0 = fmaf(h.x, m6, a0); a1 = fmaf(h.y, m6, a1);
            h = __half22float2(g7); a0 = fmaf(h.x, m7, a0); a1 = fmaf(h.y, m7, a1);
        }
        for (; j + 4 <= j1; j += 4) {
            int s0 = rfl(ssrc[j]),     s1 = rfl(ssrc[j + 1]);
            int s2 = rfl(ssrc[j + 2]), s3 = rfl(ssrc[j + 3]);
            __half2 g0 = ((const __half2*)(Hh + (size_t)s0 * 128))[lane];
            __half2 g1 = ((const __half2*)(Hh + (size_t)s1 * 128))[lane];
            __half2 g2 = ((const __half2*)(Hh + (size_t)s2 * 128))[lane];
            __half2 g3 = ((const __half2*)(Hh + (size_t)s3 * 128))[lane];
            float m0 = dinv[s0] * di, m1 = dinv[s1] * di;
            float m2 = dinv[s2] * di, m3 = dinv[s3] * di;
            float2 h;
            h = __half22float2(g0); a0 = fmaf(h.x, m0, a0); a1 = fmaf(h.y, m0, a1);
            h = __half22float2(g1); a0 = fmaf(h.x, m1, a0); a1 = fmaf(h.y, m1, a1);
            h = __half22float2(g2); a0 = fmaf(h.x, m2, a0); a1 = fmaf(h.y, m2, a1);
            h = __half22float2(g3); a0 = fmaf(h.x, m3, a0); a1 = fmaf(h.y, m3, a1);
        }
        for (; j < j1; ++j) {
            int s0 = rfl(ssrc[j]);
            __half2 g0 = ((const __half2*)(Hh + (size_t)s0 * 128))[lane];
            float m0 = dinv[s0] * di;
            float2 h = __half22float2(g0);
            a0 = fmaf(h.x, m0, a0); a1 = fmaf(h.y, m0, a1);
        }
        a0 += bv.x; a1 += bv.y;
        a0 = fmaxf(a0, 0.f); a1 = fmaxf(a1, 0.f);
        ((__half2*)(Oh + (size_t)iu * 128))[lane] = __floats2half2_rn(a0, a1);
    }
}

// parallel partial mean-pool over fp16 features
__global__ __launch_bounds__(256) void k_pool_h(const __half* __restrict__ X,
        const int* __restrict__ batch, float* __restrict__ pooled, int N) {
    int c = threadIdx.x & 127, sub = threadIdx.x >> 7;
    int chunk = (N + gridDim.x - 1) / gridDim.x;
    int b = blockIdx.x * chunk, e = min(b + chunk, N);
    float acc = 0.f;
    int cg = -1;
    for (int n = b + sub; n < e; n += 2) {
        int g = batch[n];
        if (g != cg) {
            if (cg >= 0) atomicAdd(&pooled[cg * 128 + c], acc);
            acc = 0.f;
            cg = g;
        }
        acc += __half2float(X[(size_t)n * 128 + c]);
    }
    if (cg >= 0) atomicAdd(&pooled[cg * 128 + c], acc);
}

__global__ void k_final(const float* __restrict__ P, const int* __restrict__ batch,
        const float* __restrict__ Wl, const float* __restrict__ bl,
        float* __restrict__ out, int G, int CO, int N) {
    int t = blockIdx.x * blockDim.x + threadIdx.x;
    if (t >= G * CO) return;
    int g = t / CO, o = t % CO;
    int cnt = lowerb(batch, N, g + 1) - lowerb(batch, N, g);
    float inv = cnt > 0 ? 1.0f / (float)cnt : 0.0f;
    float acc = bl[o];
    for (int k = 0; k < 128; ++k) acc += P[g * 128 + k] * inv * Wl[k * CO + o];
    out[t] = acc;
}

// ---------------- launcher ----------------
extern "C" void kernel_launch(void* const* d_in, const int* in_sizes, int n_in,
                              void* d_out, int out_size, void* d_ws, size_t ws_size,
                              hipStream_t stream) {
    const float* x     = (const float*)d_in[0];
    const int*   ei    = (const int*)d_in[1];
    const int*   batch = (const int*)d_in[2];
    const float* W1e   = (const float*)d_in[5];
    const float* b1e   = (const float*)d_in[6];
    const float* W2e   = (const float*)d_in[9];
    const float* b2e   = (const float*)d_in[10];
    const float* Wlin  = (const float*)d_in[11];
    const float* blin  = (const float*)d_in[12];
    float* out = (float*)d_out;

    int N  = in_sizes[0] / 128;
    int E  = in_sizes[1] / 2;
    int CO = in_sizes[12];          // 10
    int G  = out_size / CO;         // 64

    const int* src = ei;
    const int* dst = ei + E;

    int cap = E / 64 + 8192;        // sub-bucket capacity (uniform-random slack)

    // workspace layout: zeroed region [segcnt | bcnt | pooled] is contiguous
    _Float16* hh  = (_Float16*)d_ws;                 // N*128 fp16
    _Float16* x1h = hh + (size_t)N * 128;            // N*128 fp16
    int2* bkt     = (int2*)(x1h + (size_t)N * 128);  // 64*cap int2
    int* segcnt   = (int*)(bkt + (size_t)64 * cap);  // N*8
    int* bcnt     = segcnt + (size_t)N * 8;          // 1024
    float* pooled = (float*)(bcnt + 1024);           // G*128
    int* off      = (int*)(pooled + (size_t)G * 128);// N+1 (pad 4)
    int* segcur   = off + (N + 4);                   // N*8
    int* ssrc     = segcur + (size_t)N * 8;          // E
    int* locscan  = ssrc + E;                        // N
    int* bsum     = locscan + N;                     // 256
    int* boff     = bsum + 256;                      // 256
    float* dinv   = (float*)(boff + 256);            // N
    _Float16* wfrag = (_Float16*)(dinv + N);         // 32768 halves (W1|W2)

    int nb = (N + 255) / 256;
    int nbkt_blocks = 1024;                          // csz <= 1024 = 4 iters x 256
    int csz = (E + nbkt_blocks - 1) / nbkt_blocks;
    int nzero = N * 8 + 1024 + G * 128;              // segcnt + bcnt + pooled

    k_zero_i32<<<(nzero + 255) / 256, 256, 0, stream>>>(segcnt, nzero);
    k_prep_w2<<<128, 256, 0, stream>>>(W1e, W2e, wfrag);

    k_bucket<<<nbkt_blocks, 256, 0, stream>>>(src, dst, bcnt, bkt, E, N, cap, csz);
    k_hist2<<<512, 256, 0, stream>>>(bkt, bcnt, segcnt, cap, N);
    k_scan1<<<nb, 256, 0, stream>>>(segcnt, locscan, bsum, dinv, N);
    k_scan2<<<1, 256, 0, stream>>>(bsum, boff, off, nb, N);
    k_scan3<<<nb, 256, 0, stream>>>(locscan, boff, segcnt, off, segcur, N);
    k_scatter_b<<<512, 256, 0, stream>>>(bkt, bcnt, segcur, ssrc, cap, N);

    int nstrips = (N + 15) / 16;
    int gemm_blocks = (nstrips * 2 + 3) / 4;

    // layer 1 (A direct from f32 x)
    k_gemm_mfma<true><<<gemm_blocks, 256, 0, stream>>>((const void*)x, wfrag, hh, N);
    k_agg<<<2048, 256, 0, stream>>>((const __half*)hh, dinv, off, ssrc, b1e, (__half*)x1h, N);
    // layer 2
    k_gemm_mfma<false><<<gemm_blocks, 256, 0, stream>>>((const void*)x1h, wfrag + 16384, hh, N);
    k_agg<<<2048, 256, 0, stream>>>((const __half*)hh, dinv, off, ssrc, b2e, (__half*)x1h, N);

    k_pool_h<<<512, 256, 0, stream>>>((const __half*)x1h, batch, pooled, N);
    k_final<<<3, 256, 0, stream>>>(pooled, batch, Wlin, blin, out, G, CO, N);
}